// Round 4
// baseline (730.579 us; speedup 1.0000x reference)
//
#include <hip/hip_runtime.h>

#define BATCH 16
#define CH 64
#define NPTS 65536
#define RX 32
#define RY 32
#define RZ 32
#define RVOX (RX * RY * RZ)   // 32768
#define HALFVOX (RVOX / 2)    // 16384 floats = 64 KB in LDS
#define NQ (NPTS / 4)         // 16384 float4 quads per (b, plane)

// ---------------- K1: per-batch coordinate mean (double accumulation) ----------------
__global__ void mean_kernel(const float* __restrict__ coords, double* __restrict__ meanAcc) {
    const int b = blockIdx.y;
    const int t = blockIdx.x * blockDim.x + threadIdx.x;  // [0, NQ)
    const float4* cb = (const float4*)(coords + (size_t)b * 3 * NPTS);
    double s[3];
#pragma unroll
    for (int d = 0; d < 3; ++d) {
        const float4 v = cb[d * NQ + t];
        s[d] = ((double)v.x + (double)v.y) + ((double)v.z + (double)v.w);
    }
#pragma unroll
    for (int off = 32; off > 0; off >>= 1) {
        s[0] += __shfl_down(s[0], off);
        s[1] += __shfl_down(s[1], off);
        s[2] += __shfl_down(s[2], off);
    }
    __shared__ double red[3][4];
    const int wave = threadIdx.x >> 6, lane = threadIdx.x & 63;
    if (lane == 0) { red[0][wave] = s[0]; red[1][wave] = s[1]; red[2][wave] = s[2]; }
    __syncthreads();
    if (threadIdx.x == 0) {
        double tx = 0, ty = 0, tz = 0;
        for (int w = 0; w < 4; ++w) { tx += red[0][w]; ty += red[1][w]; tz += red[2][w]; }
        atomicAdd(&meanAcc[b * 3 + 0], tx);
        atomicAdd(&meanAcc[b * 3 + 1], ty);
        atomicAdd(&meanAcc[b * 3 + 2], tz);
    }
}

// ---------------- K2: per-batch max of squared norm ----------------
__global__ void maxnorm_kernel(const float* __restrict__ coords,
                               const double* __restrict__ meanAcc,
                               int* __restrict__ maxAcc) {
    const int b = blockIdx.y;
    const int t = blockIdx.x * blockDim.x + threadIdx.x;  // [0, NQ)
    const float4* cb = (const float4*)(coords + (size_t)b * 3 * NPTS);
    const float mx = (float)(meanAcc[b * 3 + 0] * (1.0 / NPTS));
    const float my = (float)(meanAcc[b * 3 + 1] * (1.0 / NPTS));
    const float mz = (float)(meanAcc[b * 3 + 2] * (1.0 / NPTS));
    const float4 x = cb[0 * NQ + t];
    const float4 y = cb[1 * NQ + t];
    const float4 z = cb[2 * NQ + t];
    float m = 0.0f;
    {
        float dx = x.x - mx, dy = y.x - my, dz = z.x - mz; m = fmaxf(m, dx*dx + dy*dy + dz*dz);
        dx = x.y - mx; dy = y.y - my; dz = z.y - mz;      m = fmaxf(m, dx*dx + dy*dy + dz*dz);
        dx = x.z - mx; dy = y.z - my; dz = z.z - mz;      m = fmaxf(m, dx*dx + dy*dy + dz*dz);
        dx = x.w - mx; dy = y.w - my; dz = z.w - mz;      m = fmaxf(m, dx*dx + dy*dy + dz*dz);
    }
#pragma unroll
    for (int off = 32; off > 0; off >>= 1) m = fmaxf(m, __shfl_down(m, off));
    __shared__ float redm[4];
    const int wave = threadIdx.x >> 6, lane = threadIdx.x & 63;
    if (lane == 0) redm[wave] = m;
    __syncthreads();
    if (threadIdx.x == 0) {
        float tmax = fmaxf(fmaxf(redm[0], redm[1]), fmaxf(redm[2], redm[3]));
        atomicMax(&maxAcc[b], __float_as_int(tmax));  // norm2 >= 0 -> int-bit compare valid
    }
}

// ---------------- K3: per-point normalize + voxel index (u16). No count atomics. -------
__global__ void point_kernel(const float* __restrict__ coords,
                             const double* __restrict__ meanAcc,
                             const int* __restrict__ maxAcc,
                             float* __restrict__ normc,
                             unsigned short* __restrict__ idx16) {
    const int t = blockIdx.x * blockDim.x + threadIdx.x;
    const int b = t >> 14;          // NQ = 16384 quads per plane
    const int q = t & (NQ - 1);
    const float denom = 2.0f * sqrtf(__int_as_float(maxAcc[b]));
    const float4* cb = (const float4*)(coords + (size_t)b * 3 * NPTS);
    float4* nb = (float4*)(normc + (size_t)b * 3 * NPTS);
    int vx[3][4];
#pragma unroll
    for (int d = 0; d < 3; ++d) {
        const float m = (float)(meanAcc[b * 3 + d] * (1.0 / NPTS));
        float4 v = cb[d * NQ + q];
        float4 s;
        s.x = fminf(fmaxf(((v.x - m) / denom + 0.5f) * 32.0f, 0.0f), 31.0f);
        s.y = fminf(fmaxf(((v.y - m) / denom + 0.5f) * 32.0f, 0.0f), 31.0f);
        s.z = fminf(fmaxf(((v.z - m) / denom + 0.5f) * 32.0f, 0.0f), 31.0f);
        s.w = fminf(fmaxf(((v.w - m) / denom + 0.5f) * 32.0f, 0.0f), 31.0f);
        nb[d * NQ + q] = s;
        vx[d][0] = (int)rintf(s.x);
        vx[d][1] = (int)rintf(s.y);
        vx[d][2] = (int)rintf(s.z);
        vx[d][3] = (int)rintf(s.w);
    }
    ushort4 o;
    o.x = (unsigned short)(vx[0][0] * (RY * RZ) + vx[1][0] * RZ + vx[2][0]);
    o.y = (unsigned short)(vx[0][1] * (RY * RZ) + vx[1][1] * RZ + vx[2][1]);
    o.z = (unsigned short)(vx[0][2] * (RY * RZ) + vx[1][2] * RZ + vx[2][2]);
    o.w = (unsigned short)(vx[0][3] * (RY * RZ) + vx[1][3] * RZ + vx[2][3]);
    ((ushort4*)(idx16 + (size_t)b * NPTS))[q] = o;
}

// ---------------- K3b: per-batch counts via 64 KB packed-u16 LDS grid ----------------
// 16 blocks (one per batch) x 1024 threads. Counts fit u16 (max ~127 for this data).
__global__ __launch_bounds__(1024) void count_kernel(const unsigned short* __restrict__ idx16,
                                                     float* __restrict__ counts) {
    __shared__ unsigned int cnt[RVOX / 2];  // 32768 u16 packed in 16384 u32 = 64 KB
    const int b = blockIdx.x;
    const int tid = threadIdx.x;
    for (int i = tid; i < RVOX / 2; i += 1024) cnt[i] = 0u;
    __syncthreads();
    const ushort4* is = (const ushort4*)(idx16 + (size_t)b * NPTS);
#pragma unroll 4
    for (int i = tid; i < NQ; i += 1024) {
        const ushort4 v = is[i];
        atomicAdd(&cnt[v.x >> 1], 1u << ((v.x & 1) * 16));
        atomicAdd(&cnt[v.y >> 1], 1u << ((v.y & 1) * 16));
        atomicAdd(&cnt[v.z >> 1], 1u << ((v.z & 1) * 16));
        atomicAdd(&cnt[v.w >> 1], 1u << ((v.w & 1) * 16));
    }
    __syncthreads();
    float* cb = counts + (size_t)b * RVOX;
    for (int i = tid; i < RVOX; i += 1024) {
        cb[i] = (float)((cnt[i >> 1] >> ((i & 1) * 16)) & 0xFFFFu);
    }
}

// ---------------- K4: per-(b,c) LDS-privatized accumulation, 2 half-grid passes --------
// grid = (CH, BATCH), block = 512, LDS 64 KB -> 2 blocks/CU = 16 waves/CU (4/SIMD),
// __launch_bounds__(512,4) -> 128-VGPR budget for an explicit 2x8 register pipeline.
__global__ __launch_bounds__(512, 4) void accum_kernel(const float* __restrict__ features,
                                                       const unsigned short* __restrict__ idx16,
                                                       const float* __restrict__ counts,
                                                       float* __restrict__ out) {
    __shared__ float g[HALFVOX];  // 64 KB
    const int c = blockIdx.x;
    const int b = blockIdx.y;
    const int tid = threadIdx.x;
    const float4* fs = (const float4*)(features + ((size_t)(b * CH + c)) * NPTS);
    const ushort4* is = (const ushort4*)(idx16 + (size_t)b * NPTS);
    const float* cb = counts + (size_t)b * RVOX;
    float* ob = out + ((size_t)(b * CH + c)) * RVOX;

#pragma unroll
    for (int half = 0; half < 2; ++half) {
        for (int i = tid; i < HALFVOX / 4; i += 512) ((float4*)g)[i] = make_float4(0, 0, 0, 0);
        __syncthreads();
        const unsigned short want = (unsigned short)half;

        // NQ = 16384 quads / 512 threads = 32 quads per thread, in 4 groups of 8,
        // double-buffered in registers: group k+1 loads overlap group k processing.
        float4 F[2][8];
        ushort4 I[2][8];
#pragma unroll
        for (int j = 0; j < 8; ++j) {
            F[0][j] = fs[tid + j * 512];
            I[0][j] = is[tid + j * 512];
        }
#pragma unroll
        for (int grp = 0; grp < 4; ++grp) {
            const int cur = grp & 1, nxt = cur ^ 1;
            if (grp < 3) {
#pragma unroll
                for (int j = 0; j < 8; ++j) {
                    F[nxt][j] = fs[tid + ((grp + 1) * 8 + j) * 512];
                    I[nxt][j] = is[tid + ((grp + 1) * 8 + j) * 512];
                }
            }
#pragma unroll
            for (int j = 0; j < 8; ++j) {
                const float4 f = F[cur][j];
                const ushort4 v = I[cur][j];
                if ((v.x >> 14) == want) atomicAdd(&g[v.x & (HALFVOX - 1)], f.x);
                if ((v.y >> 14) == want) atomicAdd(&g[v.y & (HALFVOX - 1)], f.y);
                if ((v.z >> 14) == want) atomicAdd(&g[v.z & (HALFVOX - 1)], f.z);
                if ((v.w >> 14) == want) atomicAdd(&g[v.w & (HALFVOX - 1)], f.w);
            }
        }
        __syncthreads();
        // write out this half, fused divide-by-count
        const float* ch = cb + half * HALFVOX;
        float* oh = ob + half * HALFVOX;
        for (int i = tid; i < HALFVOX / 4; i += 512) {
            const float4 c4 = ((const float4*)ch)[i];
            float4 v = ((const float4*)g)[i];
            v.x /= fmaxf(c4.x, 1.0f);
            v.y /= fmaxf(c4.y, 1.0f);
            v.z /= fmaxf(c4.z, 1.0f);
            v.w /= fmaxf(c4.w, 1.0f);
            ((float4*)oh)[i] = v;
        }
        __syncthreads();  // protect g before next-half re-zero
    }
}

extern "C" void kernel_launch(void* const* d_in, const int* in_sizes, int n_in,
                              void* d_out, int out_size, void* d_ws, size_t ws_size,
                              hipStream_t stream) {
    const float* features = (const float*)d_in[0];  // [16, 64, 65536]
    const float* coords = (const float*)d_in[1];    // [16, 3, 65536]
    float* out = (float*)d_out;                              // [16,64,32,32,32]
    float* normc = out + (size_t)BATCH * CH * RVOX;          // [16,3,65536]

    // ws layout: [0,384) double meanAcc[16*3]; [384,448) int maxAcc[16];
    //            [512, 512+2MiB) float counts[16*32768];
    //            then ushort idx16[16*65536] (2 MiB)
    char* ws = (char*)d_ws;
    double* meanAcc = (double*)ws;
    int* maxAcc = (int*)(ws + 384);
    float* counts = (float*)(ws + 512);
    unsigned short* idx16 = (unsigned short*)(ws + 512 + (size_t)BATCH * RVOX * 4);

    // only meanAcc/maxAcc need zeroing (counts fully written by count_kernel)
    hipMemsetAsync(ws, 0, 512, stream);

    dim3 gred(NQ / 256, BATCH);  // (64, 16)
    mean_kernel<<<gred, 256, 0, stream>>>(coords, meanAcc);
    maxnorm_kernel<<<gred, 256, 0, stream>>>(coords, meanAcc, maxAcc);

    point_kernel<<<(BATCH * NQ) / 256, 256, 0, stream>>>(coords, meanAcc, maxAcc,
                                                         normc, idx16);

    count_kernel<<<BATCH, 1024, 0, stream>>>(idx16, counts);

    accum_kernel<<<dim3(CH, BATCH), 512, 0, stream>>>(features, idx16, counts, out);
}